// Round 1
// baseline (312.134 us; speedup 1.0000x reference)
//
#include <hip/hip_runtime.h>

#define DEV __device__ __forceinline__

typedef __bf16 bf16x8 __attribute__((ext_vector_type(8)));
typedef float f32x4 __attribute__((ext_vector_type(4)));

// ---------- helpers ----------
DEV float blo(unsigned u) { return __builtin_bit_cast(float, u << 16); }
DEV float bhi(unsigned u) { return __builtin_bit_cast(float, u & 0xFFFF0000u); }
DEV unsigned short f2b(float f) {
  unsigned u = __builtin_bit_cast(unsigned, f);
  return (unsigned short)((u + 0x7FFFu + ((u >> 16) & 1u)) >> 16);
}
DEV float sigf(float x) { return 1.0f / (1.0f + expf(-x)); }

DEV void llds16(const void* g, void* l) {
  __builtin_amdgcn_global_load_lds(
      (__attribute__((address_space(1))) void*)(void*)g,
      (__attribute__((address_space(3))) void*)l, 16, 0, 0);
}

DEV void unpack8(uint4 u, float* d) {
  d[0] = blo(u.x); d[1] = bhi(u.x); d[2] = blo(u.y); d[3] = bhi(u.y);
  d[4] = blo(u.z); d[5] = bhi(u.z); d[6] = blo(u.w); d[7] = bhi(u.w);
}

// ---------- fp32 -> bf16 conversion ----------
__global__ __launch_bounds__(256) void cvt_bf16_kernel(
    const float* __restrict__ src, unsigned short* __restrict__ dst, int n4) {
  int i = blockIdx.x * 256 + threadIdx.x;
  if (i < n4) {
    float4 f = ((const float4*)src)[i];
    ushort4 o;
    o.x = f2b(f.x); o.y = f2b(f.y); o.z = f2b(f.z); o.w = f2b(f.w);
    ((ushort4*)dst)[i] = o;
  }
}

// ---------- GEMM: C[m][n] = sum_k A[m][k]*B[n][k]  (both row-major, bf16 in) ----------
// 128x128 tile, BK=32, 4 waves, 16x16x32 bf16 MFMA, global_load_lds staging.
// Columns >= act_col0 get  v = tanh(v + bias[col-act_col0])  (fused sensor layer 1).
template <int OUTF>  // 0 = bf16 out, 1 = fp32 out
__global__ __launch_bounds__(256, 2) void gemm_bt_kernel(
    const unsigned short* __restrict__ A, const unsigned short* __restrict__ B,
    void* __restrict__ Cout, int M, int N, int K, int act_col0,
    const float* __restrict__ bias) {
  __shared__ unsigned short As[128 * 32];
  __shared__ unsigned short Bs[128 * 32];
  const int tid = threadIdx.x;
  const int lane = tid & 63;
  const int w = tid >> 6;
  const int wr = w >> 1, wc = w & 1;
  const int ln15 = lane & 15, hi = lane >> 4;
  const int m0 = blockIdx.y * 128;
  const int n0 = blockIdx.x * 128;

  f32x4 acc[4][4] = {};
  const int nk = K >> 5;
  for (int kt = 0; kt < nk; ++kt) {
    const int kbase = kt * 32;
#pragma unroll
    for (int i = 0; i < 2; ++i) {
      int idx = i * 256 + tid;
      int row = idx >> 2, ch = idx & 3;
      int lb = (i * 256 + (tid >> 6) * 64) * 16;
      llds16(A + (size_t)(m0 + row) * K + kbase + ch * 8, (char*)As + lb);
      llds16(B + (size_t)(n0 + row) * K + kbase + ch * 8, (char*)Bs + lb);
    }
    __syncthreads();
    bf16x8 af[4], bf[4];
#pragma unroll
    for (int i = 0; i < 4; ++i) {
      af[i] = *(const bf16x8*)((const char*)As + (wr * 64 + i * 16 + ln15) * 64 + hi * 16);
      bf[i] = *(const bf16x8*)((const char*)Bs + (wc * 64 + i * 16 + ln15) * 64 + hi * 16);
    }
#pragma unroll
    for (int i = 0; i < 4; ++i)
#pragma unroll
      for (int j = 0; j < 4; ++j)
        acc[i][j] = __builtin_amdgcn_mfma_f32_16x16x32_bf16(af[i], bf[j], acc[i][j], 0, 0, 0);
    __syncthreads();
  }
  // epilogue: C/D layout col=lane&15, row=(lane>>4)*4+reg (m89-verified)
#pragma unroll
  for (int i = 0; i < 4; ++i) {
    int rowb = m0 + wr * 64 + i * 16 + hi * 4;
#pragma unroll
    for (int j = 0; j < 4; ++j) {
      int col = n0 + wc * 64 + j * 16 + ln15;
#pragma unroll
      for (int r = 0; r < 4; ++r) {
        float v = acc[i][j][r];
        if (col >= act_col0) v = tanhf(v + bias[col - act_col0]);
        size_t off = (size_t)(rowb + r) * N + col;
        if (OUTF == 0) ((unsigned short*)Cout)[off] = f2b(v);
        else ((float*)Cout)[off] = v;
      }
    }
  }
}

// ---------- sensor layer 2: lc = sigmoid(h1 @ w2.T + b2) ----------
__global__ __launch_bounds__(256) void sensor2_kernel(
    const unsigned short* __restrict__ QKVH, const float* __restrict__ w2,
    const float* __restrict__ b2, float* __restrict__ LC) {
  const int tid = threadIdx.x;
  const int h = tid & 15, r = tid >> 4;
  const int m = blockIdx.x * 16 + r;
  const unsigned short* hrow = QKVH + (size_t)m * 3328 + 3072;
  const float* wrow = w2 + h * 256;
  float acc = 0.0f;
  for (int d = 0; d < 256; d += 8) {
    uint4 hv = *(const uint4*)(hrow + d);
    float4 wa = *(const float4*)(wrow + d);
    float4 wb = *(const float4*)(wrow + d + 4);
    acc = fmaf(blo(hv.x), wa.x, acc); acc = fmaf(bhi(hv.x), wa.y, acc);
    acc = fmaf(blo(hv.y), wa.z, acc); acc = fmaf(bhi(hv.y), wa.w, acc);
    acc = fmaf(blo(hv.z), wb.x, acc); acc = fmaf(bhi(hv.z), wb.y, acc);
    acc = fmaf(blo(hv.w), wb.z, acc); acc = fmaf(bhi(hv.w), wb.w, acc);
  }
  LC[(size_t)m * 16 + h] = sigf(acc + b2[h]);
}

// ---------- scan pass A: per-chunk scan from zero -> M (fp32), P = prod(lam) ----------
// layout: 256 thr = 4 e-groups(16 e each) x 64 f. chunk L=64.
__global__ __launch_bounds__(256) void scan_passA_kernel(
    const unsigned short* __restrict__ QKVH, const float* __restrict__ LC,
    const float* __restrict__ decay, float* __restrict__ MS, float* __restrict__ P) {
  __shared__ unsigned short kL[4096], vL[4096];
  __shared__ float lamL[4096];
  __shared__ float sigL[64], lcL[64];
  const int tid = threadIdx.x;
  const int c = blockIdx.x, h = blockIdx.y, b = blockIdx.z;
  const int t0 = c * 64;
  const int eg = tid & 3, fo = tid >> 2, e0 = eg * 16;

#pragma unroll
  for (int i = 0; i < 2; ++i) {
    int idx = i * 256 + tid;
    int row = idx >> 3, ch = idx & 7;
    size_t g = (size_t)(b * 2048 + t0 + row) * 3328 + h * 64 + ch * 8;
    int lb = (i * 256 + (tid >> 6) * 64) * 16;
    llds16(QKVH + g + 1024, (char*)kL + lb);
    llds16(QKVH + g + 2048, (char*)vL + lb);
  }
  if (tid < 64) sigL[tid] = sigf(decay[h * 64 + tid]);
  else if (tid < 128) lcL[tid - 64] = LC[(size_t)(b * 2048 + t0 + tid - 64) * 16 + h];
  __syncthreads();
#pragma unroll
  for (int i = 0; i < 16; ++i) {
    int idx = i * 256 + tid;
    lamL[idx] = fminf(sigL[idx & 63] * (1.0f + 0.2f * lcL[idx >> 6]), 0.9995f);
  }
  __syncthreads();

  float S[16], Pr[16];
#pragma unroll
  for (int i = 0; i < 16; ++i) { S[i] = 0.0f; Pr[i] = 1.0f; }

  for (int t = 0; t < 64; ++t) {
    float lam[16], kk[16];
#pragma unroll
    for (int j = 0; j < 4; ++j) {
      f32x4 l4 = *(const f32x4*)&lamL[t * 64 + e0 + j * 4];
      lam[j * 4 + 0] = l4[0]; lam[j * 4 + 1] = l4[1];
      lam[j * 4 + 2] = l4[2]; lam[j * 4 + 3] = l4[3];
    }
    uint4 k0 = *(const uint4*)&kL[t * 64 + e0];
    uint4 k1 = *(const uint4*)&kL[t * 64 + e0 + 8];
    unpack8(k0, kk); unpack8(k1, kk + 8);
    float vf = blo((unsigned)vL[t * 64 + fo]);
#pragma unroll
    for (int i = 0; i < 16; ++i) {
      S[i] = fmaf(S[i], lam[i], kk[i] * vf);
      Pr[i] *= lam[i];
    }
  }
  size_t slot = (size_t)((b * 16 + h) * 32 + c);
  float* Mp = MS + slot * 4096;
#pragma unroll
  for (int i = 0; i < 16; ++i) Mp[(e0 + i) * 64 + fo] = S[i];
  if (fo == 0) {
#pragma unroll
    for (int i = 0; i < 16; ++i) P[slot * 64 + e0 + i] = Pr[i];
  }
}

// ---------- scan pass B: sequential chunk-state composition, in-place in MS ----------
__global__ __launch_bounds__(256) void scan_passB_kernel(
    float* __restrict__ MS, const float* __restrict__ P) {
  const int bh = blockIdx.x;
  const int tid = threadIdx.x;
  const int eg = tid & 3, fo = tid >> 2, e0 = eg * 16;
  float S[16];
#pragma unroll
  for (int i = 0; i < 16; ++i) S[i] = 0.0f;
  for (int c = 0; c < 32; ++c) {
    float* Mp = MS + ((size_t)bh * 32 + c) * 4096;
    const float* Pp = P + ((size_t)bh * 32 + c) * 64 + e0;
    float m[16], p[16];
#pragma unroll
    for (int i = 0; i < 16; ++i) m[i] = Mp[(e0 + i) * 64 + fo];
#pragma unroll
    for (int i = 0; i < 16; ++i) p[i] = Pp[i];
#pragma unroll
    for (int i = 0; i < 16; ++i) {
      Mp[(e0 + i) * 64 + fo] = S[i];       // store S_in(c)
      S[i] = fmaf(p[i], S[i], m[i]);       // advance to S_in(c+1)
    }
  }
}

// ---------- scan pass C: re-run chunk from true S_in, emit y ----------
__global__ __launch_bounds__(256) void scan_passC_kernel(
    const unsigned short* __restrict__ QKVH, const float* __restrict__ LC,
    const float* __restrict__ decay, const float* __restrict__ MS,
    unsigned short* __restrict__ Y) {
  __shared__ unsigned short qL[4096], kL[4096], vL[4096];
  __shared__ float lamL[4096];
  __shared__ float sigL[64], lcL[64];
  const int tid = threadIdx.x;
  const int c = blockIdx.x, h = blockIdx.y, b = blockIdx.z;
  const int t0 = c * 64;
  const int eg = tid & 3, fo = tid >> 2, e0 = eg * 16;

#pragma unroll
  for (int i = 0; i < 2; ++i) {
    int idx = i * 256 + tid;
    int row = idx >> 3, ch = idx & 7;
    size_t g = (size_t)(b * 2048 + t0 + row) * 3328 + h * 64 + ch * 8;
    int lb = (i * 256 + (tid >> 6) * 64) * 16;
    llds16(QKVH + g,        (char*)qL + lb);
    llds16(QKVH + g + 1024, (char*)kL + lb);
    llds16(QKVH + g + 2048, (char*)vL + lb);
  }
  if (tid < 64) sigL[tid] = sigf(decay[h * 64 + tid]);
  else if (tid < 128) lcL[tid - 64] = LC[(size_t)(b * 2048 + t0 + tid - 64) * 16 + h];
  __syncthreads();
#pragma unroll
  for (int i = 0; i < 16; ++i) {
    int idx = i * 256 + tid;
    lamL[idx] = fminf(sigL[idx & 63] * (1.0f + 0.2f * lcL[idx >> 6]), 0.9995f);
  }
  const float* Sp = MS + ((size_t)((b * 16 + h) * 32 + c)) * 4096;
  float S[16];
#pragma unroll
  for (int i = 0; i < 16; ++i) S[i] = Sp[(e0 + i) * 64 + fo];
  __syncthreads();

  unsigned short* Yp = Y + (size_t)(b * 2048 + t0) * 1024 + h * 64 + fo;
  for (int t = 0; t < 64; ++t) {
    float lam[16], kk[16], qq[16];
#pragma unroll
    for (int j = 0; j < 4; ++j) {
      f32x4 l4 = *(const f32x4*)&lamL[t * 64 + e0 + j * 4];
      lam[j * 4 + 0] = l4[0]; lam[j * 4 + 1] = l4[1];
      lam[j * 4 + 2] = l4[2]; lam[j * 4 + 3] = l4[3];
    }
    uint4 k0 = *(const uint4*)&kL[t * 64 + e0];
    uint4 k1 = *(const uint4*)&kL[t * 64 + e0 + 8];
    unpack8(k0, kk); unpack8(k1, kk + 8);
    uint4 q0 = *(const uint4*)&qL[t * 64 + e0];
    uint4 q1 = *(const uint4*)&qL[t * 64 + e0 + 8];
    unpack8(q0, qq); unpack8(q1, qq + 8);
    float vf = blo((unsigned)vL[t * 64 + fo]);
    float acc = 0.0f;
#pragma unroll
    for (int i = 0; i < 16; ++i) {
      S[i] = fmaf(S[i], lam[i], kk[i] * vf);   // update first (matches reference)
      acc = fmaf(qq[i], S[i], acc);
    }
    acc += __shfl_xor(acc, 1);
    acc += __shfl_xor(acc, 2);
    if (eg == 0) Yp[(size_t)t * 1024] = f2b(acc);
  }
}

// ---------- host launch ----------
extern "C" void kernel_launch(void* const* d_in, const int* in_sizes, int n_in,
                              void* d_out, int out_size, void* d_ws, size_t ws_size,
                              hipStream_t stream) {
  (void)in_sizes; (void)n_in; (void)out_size; (void)ws_size;
  const float* x     = (const float*)d_in[0];
  const float* q_w   = (const float*)d_in[1];
  const float* k_w   = (const float*)d_in[2];
  const float* v_w   = (const float*)d_in[3];
  const float* o_w   = (const float*)d_in[4];
  const float* cs_w1 = (const float*)d_in[5];
  const float* cs_b1 = (const float*)d_in[6];
  const float* cs_w2 = (const float*)d_in[7];
  const float* cs_b2 = (const float*)d_in[8];
  const float* decay = (const float*)d_in[9];
  float* out = (float*)d_out;

  char* ws = (char*)d_ws;
  unsigned short* XB   = (unsigned short*)(ws);                 // 16,777,216 B
  unsigned short* WCAT = (unsigned short*)(ws + 16777216);      //  6,815,744 B
  unsigned short* OWB  = (unsigned short*)(ws + 23592960);      //  2,097,152 B
  unsigned short* QKVH = (unsigned short*)(ws + 25690112);      // 54,525,952 B
  float*          LCb  = (float*)(ws + 80216064);               //    524,288 B
  float*          MS   = (float*)(ws + 80740352);               // 33,554,432 B
  float*          Pb   = (float*)(ws + 114294784);              //    524,288 B
  unsigned short* YB   = (unsigned short*)(ws + 114819072);     // 16,777,216 B

  // 1) bf16 conversions
  cvt_bf16_kernel<<<8192, 256, 0, stream>>>(x, XB, 2097152);
  cvt_bf16_kernel<<<1024, 256, 0, stream>>>(q_w, WCAT, 262144);
  cvt_bf16_kernel<<<1024, 256, 0, stream>>>(k_w, WCAT + 1048576, 262144);
  cvt_bf16_kernel<<<1024, 256, 0, stream>>>(v_w, WCAT + 2097152, 262144);
  cvt_bf16_kernel<<<256,  256, 0, stream>>>(cs_w1, WCAT + 3145728, 65536);
  cvt_bf16_kernel<<<1024, 256, 0, stream>>>(o_w, OWB, 262144);

  // 2) fused q|k|v|h1 GEMM: [8192x1024] @ [3328x1024]^T, tanh+bias on cols >=3072
  gemm_bt_kernel<0><<<dim3(26, 64), 256, 0, stream>>>(XB, WCAT, QKVH, 8192, 3328,
                                                      1024, 3072, cs_b1);
  // 3) sensor layer 2 -> lc
  sensor2_kernel<<<512, 256, 0, stream>>>(QKVH, cs_w2, cs_b2, LCb);

  // 4) chunked scan (L=64, C=32)
  scan_passA_kernel<<<dim3(32, 16, 4), 256, 0, stream>>>(QKVH, LCb, decay, MS, Pb);
  scan_passB_kernel<<<64, 256, 0, stream>>>(MS, Pb);
  scan_passC_kernel<<<dim3(32, 16, 4), 256, 0, stream>>>(QKVH, LCb, decay, MS, YB);

  // 5) o-projection: [8192x1024] @ [1024x1024]^T -> fp32 out
  gemm_bt_kernel<1><<<dim3(8, 64), 256, 0, stream>>>(YB, OWB, out, 8192, 1024,
                                                     1024, 1 << 30, nullptr);
}